// Round 11
// baseline (354.280 us; speedup 1.0000x reference)
//
#include <hip/hip_runtime.h>
#include <hip/hip_bf16.h>
#include <stdint.h>

// Problem: B=2, S=4096, D=512, H=8, hd=64. fp32 in/out, bf16 MFMA internally.
// Dispatches: cvt_all -> gemm_qkv -> flash -> gemm_out.
// R18 (v13): flash drops LDS staging ENTIRELY (m169 precedent: K/V are L2/L3
// resident; staging cache-fitting data is pure overhead). Every MFMA fragment
// is a per-lane 16B contiguous chunk of the natural K / V^T layout, loaded
// directly with global_load_dwordx4; repeats served by L1. Deletes all
// barriers, global_load_lds DMA, ds_reads, bank conflicts, and LDS (0 bytes).
// K fragments register-double-buffered (ak0/ak1 macro swap); V loads issue at
// tile start and are consumed ~300cyc later under QK+softmax. v8b math
// otherwise verbatim (32x32x16 MFMA, permlane softmax, ones-MFMA row-sum).
// Non-flash kernels unchanged (R6).
//
// ws layout:
//   [0,   8MB)  Xb    bf16 [8192,512]
//   [8,  10MB)  Wqt/Wkt/Wvt/Wot bf16 [512,512] each ([n][k]; QKV contiguous)
//   [10, 18MB)  Qb    bf16 [B,H,S,64]  (pre-scaled by 0.125*log2e)
//   [18, 26MB)  Kb    bf16 [B,H,S,64]
//   [26, 34MB)  Vtb   bf16 [B,H,64,S]
//   [34, 42MB)  Atb   bf16 [B,S,512]

typedef __bf16 bf16x8 __attribute__((ext_vector_type(8)));
typedef float f32x4 __attribute__((ext_vector_type(4)));
typedef float f32x16 __attribute__((ext_vector_type(16)));

using as1_void = __attribute__((address_space(1))) void;
using as3_void = __attribute__((address_space(3))) void;

__device__ __forceinline__ void gload16(const void* g, void* l) {
    __builtin_amdgcn_global_load_lds((const as1_void*)g, (as3_void*)l, 16, 0, 0);
}

__device__ __forceinline__ f32x4 mfma16(bf16x8 a, bf16x8 b, f32x4 c) {
    return __builtin_amdgcn_mfma_f32_16x16x32_bf16(a, b, c, 0, 0, 0);
}

__device__ __forceinline__ f32x16 mfma32(bf16x8 a, bf16x8 b, f32x16 c) {
    return __builtin_amdgcn_mfma_f32_32x32x16_bf16(a, b, c, 0, 0, 0);
}

__device__ __forceinline__ uint32_t pkbf(float a, float b) {
    union { __hip_bfloat16 h[2]; uint32_t u; } r;
    r.h[0] = __float2bfloat16(a);   // low 16 = even element
    r.h[1] = __float2bfloat16(b);
    return r.u;
}

// Exchange: a's hi-32-lane values <-> b's lo-32-lane values.
__device__ __forceinline__ void pl32swap(uint32_t& a, uint32_t& b) {
#if __has_builtin(__builtin_amdgcn_permlane32_swap)
    typedef unsigned int uint32x2_t __attribute__((ext_vector_type(2)));
    uint32x2_t r = __builtin_amdgcn_permlane32_swap(a, b, false, false);
    a = r[0];
    b = r[1];
#else
    asm volatile("v_permlane32_swap_b32 %0, %1" : "+v"(a), "+v"(b));
#endif
}

// ---------------------------------------------------------------- converts (fused)
__global__ void cvt_all(const float* __restrict__ X, __hip_bfloat16* __restrict__ Xb,
                        const float* __restrict__ w0, const float* __restrict__ w1,
                        const float* __restrict__ w2, const float* __restrict__ w3,
                        __hip_bfloat16* __restrict__ o0, __hip_bfloat16* __restrict__ o1,
                        __hip_bfloat16* __restrict__ o2, __hip_bfloat16* __restrict__ o3) {
    __shared__ float t[32][33];
    const int bid = blockIdx.x, tid = threadIdx.x;
    if (bid < 1024) {
        const float* W; __hip_bfloat16* O;
        switch (bid >> 8) {
            case 0: W = w0; O = o0; break;
            case 1: W = w1; O = o1; break;
            case 2: W = w2; O = o2; break;
            default: W = w3; O = o3; break;
        }
        int rem = bid & 255;
        int n0 = (rem & 15) * 32, k0 = (rem >> 4) * 32;
        int tx = tid & 31, ty = tid >> 5;
        for (int j = 0; j < 4; ++j)
            t[ty + 8 * j][tx] = W[(size_t)(k0 + ty + 8 * j) * 512 + n0 + tx];
        __syncthreads();
        for (int j = 0; j < 4; ++j)
            O[(size_t)(n0 + ty + 8 * j) * 512 + k0 + tx] = __float2bfloat16(t[tx][ty + 8 * j]);
    } else {
        int i = ((bid - 1024) * 256 + tid) * 4;   // covers exactly 8192*512
        float4 v = *reinterpret_cast<const float4*>(X + i);
        uint2 u;
        u.x = pkbf(v.x, v.y);
        u.y = pkbf(v.z, v.w);
        *reinterpret_cast<uint2*>(Xb + i) = u;
    }
}

// ---------------------------------------------------------------- fused QKV GEMM (R6)
__global__ __launch_bounds__(256, 2) void gemm_qkv(
    const __hip_bfloat16* __restrict__ A, const __hip_bfloat16* __restrict__ Bt,
    const float* __restrict__ bq, const float* __restrict__ bk, const float* __restrict__ bv,
    __hip_bfloat16* __restrict__ Qb, __hip_bfloat16* __restrict__ Kb,
    __hip_bfloat16* __restrict__ Vtb, float qs)
{
    const int K = 512;
    __shared__ __hip_bfloat16 Abuf[128 * 32];
    __shared__ __hip_bfloat16 Bbuf[128 * 32];
    const int tid = threadIdx.x, w = tid >> 6, lane = tid & 63;
    const int col = lane & 15, quad = lane >> 4;
    const int wr = w >> 1, wc = w & 1;
    const int tileN = blockIdx.x * 128, tileM = blockIdx.y * 128;

    f32x4 acc[4][4] = {};

    for (int k0 = 0; k0 < K; k0 += 32) {
        for (int i = 0; i < 2; ++i) {
            int g = w * 2 + i;
            int chunk = g * 64 + lane;
            int row = chunk >> 2, c8 = chunk & 3;
            gload16(A + (size_t)(tileM + row) * K + k0 + c8 * 8, Abuf + g * 512);
            gload16(Bt + (size_t)(tileN + row) * K + k0 + c8 * 8, Bbuf + g * 512);
        }
        __syncthreads();
        bf16x8 af[4], bfr[4];
        for (int mt = 0; mt < 4; ++mt)
            af[mt] = *reinterpret_cast<const bf16x8*>(Abuf + (wr * 64 + mt * 16 + col) * 32 + quad * 8);
        for (int nt = 0; nt < 4; ++nt)
            bfr[nt] = *reinterpret_cast<const bf16x8*>(Bbuf + (wc * 64 + nt * 16 + col) * 32 + quad * 8);
        for (int mt = 0; mt < 4; ++mt)
            for (int nt = 0; nt < 4; ++nt)
                acc[mt][nt] = mfma16(af[mt], bfr[nt], acc[mt][nt]);
        __syncthreads();
    }

    const int seg = (tileN + wc * 64) >> 9;   // wave-uniform
    const float* bias = (seg == 0) ? bq : (seg == 1) ? bk : bv;
    const float scale = (seg == 0) ? qs : 1.0f;
    __hip_bfloat16* outp = (seg == 0) ? Qb : (seg == 1) ? Kb : Vtb;

    for (int mt = 0; mt < 4; ++mt) {
        for (int nt = 0; nt < 4; ++nt) {
            int n = tileN + wc * 64 + nt * 16 + col;
            int nn = n & 511, h = nn >> 6, d = nn & 63;
            float bn = bias[nn];
            for (int r = 0; r < 4; ++r) {
                int m = tileM + wr * 64 + mt * 16 + quad * 4 + r;
                int b = m >> 12, s = m & 4095;
                float v = (acc[mt][nt][r] + bn) * scale;
                size_t off;
                if (seg < 2) off = (((size_t)(b * 8 + h) * 4096 + s) << 6) + d;
                else         off = (((size_t)(b * 8 + h) * 64 + d) << 12) + s;
                outp[off] = __float2bfloat16(v);
            }
        }
    }
}

// ---------------------------------------------------------------- final GEMM (Wo) (R6)
__global__ __launch_bounds__(256, 2) void gemm_out(
    const __hip_bfloat16* __restrict__ A, const __hip_bfloat16* __restrict__ Bt,
    const float* __restrict__ bias, float* __restrict__ out)
{
    const int N = 512, K = 512;
    __shared__ __hip_bfloat16 Abuf[128 * 32];
    __shared__ __hip_bfloat16 Bbuf[64 * 32];
    const int tid = threadIdx.x, w = tid >> 6, lane = tid & 63;
    const int col = lane & 15, quad = lane >> 4;
    const int tileN = blockIdx.x * 64, tileM = blockIdx.y * 128;

    f32x4 acc[2][4] = {};

    for (int k0 = 0; k0 < K; k0 += 32) {
        for (int i = 0; i < 2; ++i) {
            int g = w * 2 + i;
            int chunk = g * 64 + lane;
            int row = chunk >> 2, c8 = chunk & 3;
            gload16(A + (size_t)(tileM + row) * K + k0 + c8 * 8, Abuf + g * 512);
        }
        {
            int row = tid >> 2, c8 = tid & 3;
            gload16(Bt + (size_t)(tileN + row) * K + k0 + c8 * 8, Bbuf + tid * 8);
        }
        __syncthreads();
        bf16x8 af[2], bfr[4];
        for (int mt = 0; mt < 2; ++mt)
            af[mt] = *reinterpret_cast<const bf16x8*>(Abuf + (w * 32 + mt * 16 + col) * 32 + quad * 8);
        for (int nt = 0; nt < 4; ++nt)
            bfr[nt] = *reinterpret_cast<const bf16x8*>(Bbuf + (nt * 16 + col) * 32 + quad * 8);
        for (int mt = 0; mt < 2; ++mt)
            for (int nt = 0; nt < 4; ++nt)
                acc[mt][nt] = mfma16(af[mt], bfr[nt], acc[mt][nt]);
        __syncthreads();
    }

    for (int mt = 0; mt < 2; ++mt) {
        for (int nt = 0; nt < 4; ++nt) {
            int n = tileN + nt * 16 + col;
            float bn = bias[n];
            for (int r = 0; r < 4; ++r) {
                int m = tileM + w * 32 + mt * 16 + quad * 4 + r;
                out[(size_t)m * N + n] = acc[mt][nt][r] + bn;
            }
        }
    }
}

// ---------------------------------------------------------------- flash attention (v13)
// No LDS, no barriers. 4 waves x 32 q-rows, 256 thr, grid (32,16).
// Fragments loaded directly from global (L1/L2-served), K reg-double-buffered.
__global__ __launch_bounds__(256, 2) void flash(
    const __hip_bfloat16* __restrict__ Q,   // [B*H, 4096, 64] (pre-scaled)
    const __hip_bfloat16* __restrict__ Kq,  // [B*H, 4096, 64]
    const __hip_bfloat16* __restrict__ Vt,  // [B*H, 64, 4096]
    __hip_bfloat16* __restrict__ attnb)     // [B, 4096, 512]
{
    const int bh = blockIdx.y, b = bh >> 3, hq = bh & 7;
    const int tid = threadIdx.x, w = tid >> 6, lane = tid & 63;
    const int l31 = lane & 31, hh = lane >> 5;
    const int q0 = blockIdx.x * 128 + w * 32;

    const __hip_bfloat16* Qh = Q + (size_t)bh * 4096 * 64;
    const __hip_bfloat16* Kh = Kq + (size_t)bh * 4096 * 64;
    const __hip_bfloat16* Vh = Vt + (size_t)bh * 64 * 4096;

    // Q fragments (B-operand): lane q = l31, d = dk*16 + hh*8 + j
    bf16x8 aq[4];
#pragma unroll
    for (int dk = 0; dk < 4; ++dk)
        aq[dk] = *reinterpret_cast<const bf16x8*>(
            Qh + (size_t)(q0 + l31) * 64 + dk * 16 + hh * 8);

    // Per-lane fragment base pointers (natural layouts, no swizzle):
    //   ak[kg][dk](t) = Kh[(t*64 + kg*32 + l31)*64 + dk*16 + hh*8]
    //   av[dg][kb](t) = Vh[(dg*32 + l31)*4096 + t*64 + kb*16 + hh*8]
    const __hip_bfloat16* kb0 = Kh + (size_t)l31 * 64 + hh * 8;
    const __hip_bfloat16* vb0 = Vh + (size_t)l31 * 4096 + hh * 8;

    bf16x8 ones;
#pragma unroll
    for (int j = 0; j < 8; ++j) ones[j] = (__bf16)1.0f;

    const f32x16 z16 = {};
    f32x16 o[2] = {};        // D[d][q]: d = dg*32 + (reg&3)+8*(reg>>2)+4hh
    f32x16 lacc = {};        // row-sums via ones-MFMA

    bf16x8 ak0[2][4], ak1[2][4];

    // prologue: K fragments for tile 0
#pragma unroll
    for (int kg = 0; kg < 2; ++kg)
#pragma unroll
        for (int dk = 0; dk < 4; ++dk)
            ak0[kg][dk] = *reinterpret_cast<const bf16x8*>(
                kb0 + kg * (32 * 64) + dk * 16);

// Body for tile T_: AKC_ holds K(T_) fragments; loads K(T_+1) into AKN_
// (clamped re-load of tile 63 at the end — harmless). V(T_) loaded here,
// consumed after QK+softmax (~300cyc of latency hiding).
#define FLASH_BODY(T_, AKC_, AKN_)                                             \
    {                                                                          \
        const int t_ = (T_);                                                   \
        const int tn_ = (t_ < 63) ? t_ + 1 : 63;                               \
        bf16x8 av[2][4];                                                       \
        _Pragma("unroll")                                                      \
        for (int dg = 0; dg < 2; ++dg)                                         \
            _Pragma("unroll")                                                  \
            for (int kb = 0; kb < 4; ++kb)                                     \
                av[dg][kb] = *reinterpret_cast<const bf16x8*>(                 \
                    vb0 + (size_t)dg * (32 * 4096) + t_ * 64 + kb * 16);       \
        _Pragma("unroll")                                                      \
        for (int kg = 0; kg < 2; ++kg)                                         \
            _Pragma("unroll")                                                  \
            for (int dk = 0; dk < 4; ++dk)                                     \
                AKN_[kg][dk] = *reinterpret_cast<const bf16x8*>(               \
                    kb0 + (size_t)tn_ * 4096 + kg * (32 * 64) + dk * 16);      \
        f32x16 sc[2];                                                          \
        _Pragma("unroll")                                                      \
        for (int kg = 0; kg < 2; ++kg) {                                       \
            _Pragma("unroll")                                                  \
            for (int dk = 0; dk < 4; ++dk)                                     \
                sc[kg] = (dk == 0) ? mfma32(AKC_[kg][0], aq[0], z16)           \
                                   : mfma32(AKC_[kg][dk], aq[dk], sc[kg]);     \
        }                                                                      \
        uint32_t U[8][2];                                                      \
        _Pragma("unroll")                                                      \
        for (int kg = 0; kg < 2; ++kg) {                                       \
            f32x16 v = sc[kg];                                                 \
            _Pragma("unroll")                                                  \
            for (int rr = 0; rr < 4; ++rr) {                                   \
                U[kg * 4 + rr][0] = pkbf(__builtin_amdgcn_exp2f(v[rr * 4 + 0]),\
                                         __builtin_amdgcn_exp2f(v[rr * 4 + 1]));\
                U[kg * 4 + rr][1] = pkbf(__builtin_amdgcn_exp2f(v[rr * 4 + 2]),\
                                         __builtin_amdgcn_exp2f(v[rr * 4 + 3]));\
            }                                                                  \
        }                                                                      \
        bf16x8 bp[4];                                                          \
        _Pragma("unroll")                                                      \
        for (int kb = 0; kb < 4; ++kb) {                                       \
            pl32swap(U[2 * kb][0], U[2 * kb + 1][0]);                          \
            pl32swap(U[2 * kb][1], U[2 * kb + 1][1]);                          \
            union { uint32_t u[4]; bf16x8 v8; } cc;                            \
            cc.u[0] = U[2 * kb][0];     cc.u[1] = U[2 * kb][1];                \
            cc.u[2] = U[2 * kb + 1][0]; cc.u[3] = U[2 * kb + 1][1];            \
            bp[kb] = cc.v8;                                                    \
        }                                                                      \
        _Pragma("unroll")                                                      \
        for (int dg = 0; dg < 2; ++dg)                                         \
            _Pragma("unroll")                                                  \
            for (int kb = 0; kb < 4; ++kb)                                     \
                o[dg] = mfma32(av[dg][kb], bp[kb], o[dg]);                     \
        _Pragma("unroll")                                                      \
        for (int kb = 0; kb < 4; ++kb) lacc = mfma32(ones, bp[kb], lacc);      \
    }

    for (int t2 = 0; t2 < 32; ++t2) {
        FLASH_BODY(2 * t2, ak0, ak1)
        FLASH_BODY(2 * t2 + 1, ak1, ak0)
    }
#undef FLASH_BODY

    {
        float inv = 1.0f / lacc[0];
        int s = q0 + l31;
        __hip_bfloat16* dst = attnb + ((size_t)b * 4096 + s) * 512 + hq * 64;
#pragma unroll
        for (int dg = 0; dg < 2; ++dg)
#pragma unroll
            for (int rr = 0; rr < 4; ++rr) {
                uint2 u;
                u.x = pkbf(o[dg][rr * 4 + 0] * inv, o[dg][rr * 4 + 1] * inv);
                u.y = pkbf(o[dg][rr * 4 + 2] * inv, o[dg][rr * 4 + 3] * inv);
                *reinterpret_cast<uint2*>(dst + dg * 32 + rr * 8 + hh * 4) = u;
            }
    }
}

// ---------------------------------------------------------------- launch
extern "C" void kernel_launch(void* const* d_in, const int* in_sizes, int n_in,
                              void* d_out, int out_size, void* d_ws, size_t ws_size,
                              hipStream_t stream) {
    const float* X  = (const float*)d_in[0];
    const float* Wq = (const float*)d_in[1];
    const float* bq = (const float*)d_in[2];
    const float* Wk = (const float*)d_in[3];
    const float* bk = (const float*)d_in[4];
    const float* Wv = (const float*)d_in[5];
    const float* bv = (const float*)d_in[6];
    const float* Wo = (const float*)d_in[7];
    const float* bo = (const float*)d_in[8];
    float* out = (float*)d_out;

    char* ws = (char*)d_ws;
    __hip_bfloat16* Xb  = (__hip_bfloat16*)(ws);
    __hip_bfloat16* Wqt = (__hip_bfloat16*)(ws + ((size_t)8 << 20));
    __hip_bfloat16* Wkt = Wqt + 512 * 512;
    __hip_bfloat16* Wvt = Wkt + 512 * 512;
    __hip_bfloat16* Wot = Wvt + 512 * 512;
    __hip_bfloat16* Qb  = (__hip_bfloat16*)(ws + ((size_t)10 << 20));
    __hip_bfloat16* Kb  = (__hip_bfloat16*)(ws + ((size_t)18 << 20));
    __hip_bfloat16* Vtb = (__hip_bfloat16*)(ws + ((size_t)26 << 20));
    __hip_bfloat16* Atb = (__hip_bfloat16*)(ws + ((size_t)34 << 20));

    cvt_all<<<5120, 256, 0, stream>>>(X, Xb, Wq, Wk, Wv, Wo, Wqt, Wkt, Wvt, Wot);

    const float qs = 0.125f * 1.4426950408889634f;  // (1/sqrt(64)) * log2(e)
    gemm_qkv<<<dim3(12, 64), 256, 0, stream>>>(Xb, Wqt, bq, bk, bv, Qb, Kb, Vtb, qs);
    flash<<<dim3(32, 16), 256, 0, stream>>>(Qb, Kb, Vtb, Atb);
    gemm_out<<<dim3(8, 64), 256, 0, stream>>>(Atb, Wot, bo, out);
}

// Round 13
// 210.050 us; speedup vs baseline: 1.6866x; 1.6866x over previous
//
#include <hip/hip_runtime.h>
#include <hip/hip_bf16.h>
#include <stdint.h>

// Problem: B=2, S=4096, D=512, H=8, hd=64. fp32 in/out, bf16 MFMA internally.
// Dispatches: cvt_all -> gemm_qkv -> flash -> gemm_out.
// R20 (v15): R12's cvt_pk experiment FAILED numerically (v_cvt_pk_bf16_f32 is
// not RNE-equivalent; absmax 0.149) — pkbf reverted to __float2bfloat16 (m240
// was right). New mechanism this round: gemm_qkv dispatch-tail removal. Grid
// 768 blocks at 2 blocks/CU ran as 512+256 rounds (2nd round half-idle chip);
// 768 = 3x256, so __launch_bounds__(256,3) makes all 768 co-resident
// (VGPR cap 168: acc=64+frags fits; LDS 3x16KB=48KB fine). Flash = v12
// byte-identical (2-tile windows, best 94.6us).
//
// ws layout:
//   [0,   8MB)  Xb    bf16 [8192,512]
//   [8,  10MB)  Wqt/Wkt/Wvt/Wot bf16 [512,512] each ([n][k]; QKV contiguous)
//   [10, 18MB)  Qb    bf16 [B,H,S,64]  (pre-scaled by 0.125*log2e)
//   [18, 26MB)  Kb    bf16 [B,H,S,64]
//   [26, 34MB)  Vtb   bf16 [B,H,64,S]
//   [34, 42MB)  Atb   bf16 [B,S,512]

typedef __bf16 bf16x8 __attribute__((ext_vector_type(8)));
typedef float f32x4 __attribute__((ext_vector_type(4)));
typedef float f32x16 __attribute__((ext_vector_type(16)));

using as1_void = __attribute__((address_space(1))) void;
using as3_void = __attribute__((address_space(3))) void;

__device__ __forceinline__ void gload16(const void* g, void* l) {
    __builtin_amdgcn_global_load_lds((const as1_void*)g, (as3_void*)l, 16, 0, 0);
}

__device__ __forceinline__ f32x4 mfma16(bf16x8 a, bf16x8 b, f32x4 c) {
    return __builtin_amdgcn_mfma_f32_16x16x32_bf16(a, b, c, 0, 0, 0);
}

__device__ __forceinline__ f32x16 mfma32(bf16x8 a, bf16x8 b, f32x16 c) {
    return __builtin_amdgcn_mfma_f32_32x32x16_bf16(a, b, c, 0, 0, 0);
}

// fp32->bf16 pair pack, RNE via HIP cast (verified absmax 0.00195; the
// v_cvt_pk_bf16_f32 shortcut is NOT RNE-equivalent — R12 failure).
__device__ __forceinline__ uint32_t pkbf(float a, float b) {
    union { __hip_bfloat16 h[2]; uint32_t u; } r;
    r.h[0] = __float2bfloat16(a);   // low 16 = even element
    r.h[1] = __float2bfloat16(b);
    return r.u;
}

// Exchange: a's hi-32-lane values <-> b's lo-32-lane values.
__device__ __forceinline__ void pl32swap(uint32_t& a, uint32_t& b) {
#if __has_builtin(__builtin_amdgcn_permlane32_swap)
    typedef unsigned int uint32x2_t __attribute__((ext_vector_type(2)));
    uint32x2_t r = __builtin_amdgcn_permlane32_swap(a, b, false, false);
    a = r[0];
    b = r[1];
#else
    asm volatile("v_permlane32_swap_b32 %0, %1" : "+v"(a), "+v"(b));
#endif
}

// ---------------------------------------------------------------- converts (fused)
__global__ void cvt_all(const float* __restrict__ X, __hip_bfloat16* __restrict__ Xb,
                        const float* __restrict__ w0, const float* __restrict__ w1,
                        const float* __restrict__ w2, const float* __restrict__ w3,
                        __hip_bfloat16* __restrict__ o0, __hip_bfloat16* __restrict__ o1,
                        __hip_bfloat16* __restrict__ o2, __hip_bfloat16* __restrict__ o3) {
    __shared__ float t[32][33];
    const int bid = blockIdx.x, tid = threadIdx.x;
    if (bid < 1024) {
        const float* W; __hip_bfloat16* O;
        switch (bid >> 8) {
            case 0: W = w0; O = o0; break;
            case 1: W = w1; O = o1; break;
            case 2: W = w2; O = o2; break;
            default: W = w3; O = o3; break;
        }
        int rem = bid & 255;
        int n0 = (rem & 15) * 32, k0 = (rem >> 4) * 32;
        int tx = tid & 31, ty = tid >> 5;
        for (int j = 0; j < 4; ++j)
            t[ty + 8 * j][tx] = W[(size_t)(k0 + ty + 8 * j) * 512 + n0 + tx];
        __syncthreads();
        for (int j = 0; j < 4; ++j)
            O[(size_t)(n0 + ty + 8 * j) * 512 + k0 + tx] = __float2bfloat16(t[tx][ty + 8 * j]);
    } else {
        int i = ((bid - 1024) * 256 + tid) * 4;   // covers exactly 8192*512
        float4 v = *reinterpret_cast<const float4*>(X + i);
        uint2 u;
        u.x = pkbf(v.x, v.y);
        u.y = pkbf(v.z, v.w);
        *reinterpret_cast<uint2*>(Xb + i) = u;
    }
}

// ---------------------------------------------------------------- fused QKV GEMM
// Grid (12,64) = 768 blocks = 3 blocks/CU (launch_bounds 3) — single dispatch
// round, no 512+256 tail (R20 fix).
__global__ __launch_bounds__(256, 3) void gemm_qkv(
    const __hip_bfloat16* __restrict__ A, const __hip_bfloat16* __restrict__ Bt,
    const float* __restrict__ bq, const float* __restrict__ bk, const float* __restrict__ bv,
    __hip_bfloat16* __restrict__ Qb, __hip_bfloat16* __restrict__ Kb,
    __hip_bfloat16* __restrict__ Vtb, float qs)
{
    const int K = 512;
    __shared__ __hip_bfloat16 Abuf[128 * 32];
    __shared__ __hip_bfloat16 Bbuf[128 * 32];
    const int tid = threadIdx.x, w = tid >> 6, lane = tid & 63;
    const int col = lane & 15, quad = lane >> 4;
    const int wr = w >> 1, wc = w & 1;
    const int tileN = blockIdx.x * 128, tileM = blockIdx.y * 128;

    f32x4 acc[4][4] = {};

    for (int k0 = 0; k0 < K; k0 += 32) {
        for (int i = 0; i < 2; ++i) {
            int g = w * 2 + i;
            int chunk = g * 64 + lane;
            int row = chunk >> 2, c8 = chunk & 3;
            gload16(A + (size_t)(tileM + row) * K + k0 + c8 * 8, Abuf + g * 512);
            gload16(Bt + (size_t)(tileN + row) * K + k0 + c8 * 8, Bbuf + g * 512);
        }
        __syncthreads();
        bf16x8 af[4], bfr[4];
        for (int mt = 0; mt < 4; ++mt)
            af[mt] = *reinterpret_cast<const bf16x8*>(Abuf + (wr * 64 + mt * 16 + col) * 32 + quad * 8);
        for (int nt = 0; nt < 4; ++nt)
            bfr[nt] = *reinterpret_cast<const bf16x8*>(Bbuf + (wc * 64 + nt * 16 + col) * 32 + quad * 8);
        for (int mt = 0; mt < 4; ++mt)
            for (int nt = 0; nt < 4; ++nt)
                acc[mt][nt] = mfma16(af[mt], bfr[nt], acc[mt][nt]);
        __syncthreads();
    }

    const int seg = (tileN + wc * 64) >> 9;   // wave-uniform
    const float* bias = (seg == 0) ? bq : (seg == 1) ? bk : bv;
    const float scale = (seg == 0) ? qs : 1.0f;
    __hip_bfloat16* outp = (seg == 0) ? Qb : (seg == 1) ? Kb : Vtb;

    for (int mt = 0; mt < 4; ++mt) {
        for (int nt = 0; nt < 4; ++nt) {
            int n = tileN + wc * 64 + nt * 16 + col;
            int nn = n & 511, h = nn >> 6, d = nn & 63;
            float bn = bias[nn];
            for (int r = 0; r < 4; ++r) {
                int m = tileM + wr * 64 + mt * 16 + quad * 4 + r;
                int b = m >> 12, s = m & 4095;
                float v = (acc[mt][nt][r] + bn) * scale;
                size_t off;
                if (seg < 2) off = (((size_t)(b * 8 + h) * 4096 + s) << 6) + d;
                else         off = (((size_t)(b * 8 + h) * 64 + d) << 12) + s;
                outp[off] = __float2bfloat16(v);
            }
        }
    }
}

// ---------------------------------------------------------------- final GEMM (Wo) (R6)
__global__ __launch_bounds__(256, 2) void gemm_out(
    const __hip_bfloat16* __restrict__ A, const __hip_bfloat16* __restrict__ Bt,
    const float* __restrict__ bias, float* __restrict__ out)
{
    const int N = 512, K = 512;
    __shared__ __hip_bfloat16 Abuf[128 * 32];
    __shared__ __hip_bfloat16 Bbuf[64 * 32];
    const int tid = threadIdx.x, w = tid >> 6, lane = tid & 63;
    const int col = lane & 15, quad = lane >> 4;
    const int tileN = blockIdx.x * 64, tileM = blockIdx.y * 128;

    f32x4 acc[2][4] = {};

    for (int k0 = 0; k0 < K; k0 += 32) {
        for (int i = 0; i < 2; ++i) {
            int g = w * 2 + i;
            int chunk = g * 64 + lane;
            int row = chunk >> 2, c8 = chunk & 3;
            gload16(A + (size_t)(tileM + row) * K + k0 + c8 * 8, Abuf + g * 512);
        }
        {
            int row = tid >> 2, c8 = tid & 3;
            gload16(Bt + (size_t)(tileN + row) * K + k0 + c8 * 8, Bbuf + tid * 8);
        }
        __syncthreads();
        bf16x8 af[2], bfr[4];
        for (int mt = 0; mt < 2; ++mt)
            af[mt] = *reinterpret_cast<const bf16x8*>(Abuf + (w * 32 + mt * 16 + col) * 32 + quad * 8);
        for (int nt = 0; nt < 4; ++nt)
            bfr[nt] = *reinterpret_cast<const bf16x8*>(Bbuf + (nt * 16 + col) * 32 + quad * 8);
        for (int mt = 0; mt < 2; ++mt)
            for (int nt = 0; nt < 4; ++nt)
                acc[mt][nt] = mfma16(af[mt], bfr[nt], acc[mt][nt]);
        __syncthreads();
    }

    for (int mt = 0; mt < 2; ++mt) {
        for (int nt = 0; nt < 4; ++nt) {
            int n = tileN + nt * 16 + col;
            float bn = bias[n];
            for (int r = 0; r < 4; ++r) {
                int m = tileM + w * 32 + mt * 16 + quad * 4 + r;
                out[(size_t)m * N + n] = acc[mt][nt][r] + bn;
            }
        }
    }
}

// ---------------------------------------------------------------- flash attention (v12)
// v8b math (4 waves x 32 q-rows, 32x32x16 MFMA, in-register softmax), 2-tile
// windows: one __syncthreads per 2 kv-tiles. LDS 64KB: KT[2][8192]+VB[2][8192].
__global__ __launch_bounds__(256, 2) void flash(
    const __hip_bfloat16* __restrict__ Q,   // [B*H, 4096, 64] (pre-scaled)
    const __hip_bfloat16* __restrict__ Kq,  // [B*H, 4096, 64]
    const __hip_bfloat16* __restrict__ Vt,  // [B*H, 64, 4096]
    __hip_bfloat16* __restrict__ attnb)     // [B, 4096, 512]
{
    __shared__ __hip_bfloat16 KT[2][8192];  // 32 KB: [buf][tile(2)*4096 + ...]
    __shared__ __hip_bfloat16 VB[2][8192];  // 32 KB

    const int bh = blockIdx.y, b = bh >> 3, hq = bh & 7;
    const int tid = threadIdx.x, w = tid >> 6, lane = tid & 63;
    const int l31 = lane & 31, hh = lane >> 5, l7 = lane & 7;
    const int q0 = blockIdx.x * 128 + w * 32;

    const __hip_bfloat16* Qh = Q + (size_t)bh * 4096 * 64;
    const __hip_bfloat16* Kh = Kq + (size_t)bh * 4096 * 64;
    const __hip_bfloat16* Vh = Vt + (size_t)bh * 64 * 4096;

    // Q fragments (B-operand): lane q = l31, d = dk*16 + hh*8 + j
    bf16x8 aq[4];
#pragma unroll
    for (int dk = 0; dk < 4; ++dk)
        aq[dk] = *reinterpret_cast<const bf16x8*>(
            Qh + (size_t)(q0 + l31) * 64 + dk * 16 + hh * 8);

    // K/V staging: pre-swizzled global source (^ row&7), linear LDS dest.
    const __hip_bfloat16* ksrc[2];
    const __hip_bfloat16* vsrc[2];
    int ldsoff[2];
#pragma unroll
    for (int i = 0; i < 2; ++i) {
        int c = i * 256 + tid;
        int row = c >> 3, s8 = (c & 7) ^ (row & 7);
        ksrc[i] = Kh + row * 64 + s8 * 8;
        vsrc[i] = Vh + (size_t)row * 4096 + s8 * 8;
        ldsoff[i] = (i * 256 + w * 64) * 8;
    }

    bf16x8 ones;
#pragma unroll
    for (int j = 0; j < 8; ++j) ones[j] = (__bf16)1.0f;

    const f32x16 z16 = {};
    f32x16 o[2] = {};        // D[d][q]: d = dg*32 + (reg&3)+8*(reg>>2)+4hh
    f32x16 lacc = {};        // row-sums via ones-MFMA (MFMA pipe — R9 lesson)
    f32x16 sc0[2], sc1[2];   // scores for the window's two tiles

    // prologue: stage window 0 (tiles 0,1)
#pragma unroll
    for (int t2 = 0; t2 < 2; ++t2)
#pragma unroll
        for (int i = 0; i < 2; ++i) {
            gload16(ksrc[i] + (size_t)t2 * 4096, &KT[0][t2 * 4096 + ldsoff[i]]);
            gload16(vsrc[i] + (size_t)t2 * 64,  &VB[0][t2 * 4096 + ldsoff[i]]);
        }
    __syncthreads();

#define QK_T(P_, T2_, SC_)                                                      \
    _Pragma("unroll")                                                           \
    for (int kg = 0; kg < 2; ++kg) {                                            \
        _Pragma("unroll")                                                       \
        for (int dk = 0; dk < 4; ++dk) {                                        \
            bf16x8 ak = *reinterpret_cast<const bf16x8*>(                       \
                &KT[P_][(T2_) * 4096 + (kg * 32 + l31) * 64 +                   \
                        (((dk * 2 + hh) ^ l7) << 3)]);                          \
            SC_[kg] = (dk == 0) ? mfma32(ak, aq[0], z16)                        \
                                : mfma32(ak, aq[dk], SC_[kg]);                  \
        }                                                                       \
    }

#define SM_T(SC_, BP_)                                                          \
    {                                                                           \
        uint32_t U[8][2];                                                       \
        _Pragma("unroll")                                                       \
        for (int kg = 0; kg < 2; ++kg) {                                        \
            f32x16 v = SC_[kg];                                                 \
            _Pragma("unroll")                                                   \
            for (int rr = 0; rr < 4; ++rr) {                                    \
                U[kg * 4 + rr][0] = pkbf(__builtin_amdgcn_exp2f(v[rr * 4 + 0]), \
                                         __builtin_amdgcn_exp2f(v[rr * 4 + 1]));\
                U[kg * 4 + rr][1] = pkbf(__builtin_amdgcn_exp2f(v[rr * 4 + 2]), \
                                         __builtin_amdgcn_exp2f(v[rr * 4 + 3]));\
            }                                                                   \
        }                                                                       \
        _Pragma("unroll")                                                       \
        for (int kb = 0; kb < 4; ++kb) {                                        \
            pl32swap(U[2 * kb][0], U[2 * kb + 1][0]);                           \
            pl32swap(U[2 * kb][1], U[2 * kb + 1][1]);                           \
            union { uint32_t u[4]; bf16x8 v8; } cc;                             \
            cc.u[0] = U[2 * kb][0];     cc.u[1] = U[2 * kb][1];                 \
            cc.u[2] = U[2 * kb + 1][0]; cc.u[3] = U[2 * kb + 1][1];             \
            BP_[kb] = cc.v8;                                                    \
        }                                                                       \
    }

#define PV_T(P_, T2_, BP_)                                                      \
    _Pragma("unroll")                                                           \
    for (int dg = 0; dg < 2; ++dg) {                                            \
        _Pragma("unroll")                                                       \
        for (int kb = 0; kb < 4; ++kb) {                                        \
            bf16x8 av = *reinterpret_cast<const bf16x8*>(                       \
                &VB[P_][(T2_) * 4096 + (dg * 32 + l31) * 64 +                   \
                        (((kb * 2 + hh) ^ l7) << 3)]);                          \
            o[dg] = mfma32(av, BP_[kb], o[dg]);                                 \
        }                                                                       \
    }                                                                           \
    _Pragma("unroll")                                                           \
    for (int kb = 0; kb < 4; ++kb) lacc = mfma32(ones, BP_[kb], lacc);

// Window W_ (parity P_): tiles {2W, 2W+1} resident in KT/VB[P_].
// Stage next window's 2 K-tiles + 2 V-tiles into buf 1-P_ (clamped at end).
#define WINDOW(W_, P_)                                                          \
    {                                                                           \
        const int t0_ = 2 * (W_);                                               \
        int ka = t0_ + 2; if (ka > 62) ka = 62;                                 \
        int kb2 = t0_ + 3; if (kb2 > 63) kb2 = 63;                              \
        gload16(ksrc[0] + (size_t)ka * 4096, &KT[1 - (P_)][ldsoff[0]]);         \
        gload16(ksrc[1] + (size_t)ka * 4096, &KT[1 - (P_)][ldsoff[1]]);         \
        gload16(ksrc[0] + (size_t)kb2 * 4096, &KT[1 - (P_)][4096 + ldsoff[0]]); \
        gload16(ksrc[1] + (size_t)kb2 * 4096, &KT[1 - (P_)][4096 + ldsoff[1]]); \
        gload16(vsrc[0] + (size_t)ka * 64, &VB[1 - (P_)][ldsoff[0]]);           \
        gload16(vsrc[1] + (size_t)ka * 64, &VB[1 - (P_)][ldsoff[1]]);           \
        gload16(vsrc[0] + (size_t)kb2 * 64, &VB[1 - (P_)][4096 + ldsoff[0]]);   \
        gload16(vsrc[1] + (size_t)kb2 * 64, &VB[1 - (P_)][4096 + ldsoff[1]]);   \
        QK_T(P_, 0, sc0)                                                        \
        QK_T(P_, 1, sc1)                                                        \
        {                                                                       \
            bf16x8 bpA[4];                                                      \
            SM_T(sc0, bpA)                                                      \
            PV_T(P_, 0, bpA)                                                    \
        }                                                                       \
        {                                                                       \
            bf16x8 bpB[4];                                                      \
            SM_T(sc1, bpB)                                                      \
            PV_T(P_, 1, bpB)                                                    \
        }                                                                       \
        __syncthreads();                                                        \
    }

    for (int wh = 0; wh < 16; ++wh) {
        WINDOW(2 * wh, 0)
        WINDOW(2 * wh + 1, 1)
    }
#undef WINDOW
#undef PV_T
#undef SM_T
#undef QK_T

    {
        float inv = 1.0f / lacc[0];
        int s = q0 + l31;
        __hip_bfloat16* dst = attnb + ((size_t)b * 4096 + s) * 512 + hq * 64;
#pragma unroll
        for (int dg = 0; dg < 2; ++dg)
#pragma unroll
            for (int rr = 0; rr < 4; ++rr) {
                uint2 u;
                u.x = pkbf(o[dg][rr * 4 + 0] * inv, o[dg][rr * 4 + 1] * inv);
                u.y = pkbf(o[dg][rr * 4 + 2] * inv, o[dg][rr * 4 + 3] * inv);
                *reinterpret_cast<uint2*>(dst + dg * 32 + rr * 8 + hh * 4) = u;
            }
    }
}

// ---------------------------------------------------------------- launch
extern "C" void kernel_launch(void* const* d_in, const int* in_sizes, int n_in,
                              void* d_out, int out_size, void* d_ws, size_t ws_size,
                              hipStream_t stream) {
    const float* X  = (const float*)d_in[0];
    const float* Wq = (const float*)d_in[1];
    const float* bq = (const float*)d_in[2];
    const float* Wk = (const float*)d_in[3];
    const float* bk = (const float*)d_in[4];
    const float* Wv = (const float*)d_in[5];
    const float* bv = (const float*)d_in[6];
    const float* Wo = (const float*)d_in[7];
    const float* bo = (const float*)d_in[8];
    float* out = (float*)d_out;

    char* ws = (char*)d_ws;
    __hip_bfloat16* Xb  = (__hip_bfloat16*)(ws);
    __hip_bfloat16* Wqt = (__hip_bfloat16*)(ws + ((size_t)8 << 20));
    __hip_bfloat16* Wkt = Wqt + 512 * 512;
    __hip_bfloat16* Wvt = Wkt + 512 * 512;
    __hip_bfloat16* Wot = Wvt + 512 * 512;
    __hip_bfloat16* Qb  = (__hip_bfloat16*)(ws + ((size_t)10 << 20));
    __hip_bfloat16* Kb  = (__hip_bfloat16*)(ws + ((size_t)18 << 20));
    __hip_bfloat16* Vtb = (__hip_bfloat16*)(ws + ((size_t)26 << 20));
    __hip_bfloat16* Atb = (__hip_bfloat16*)(ws + ((size_t)34 << 20));

    cvt_all<<<5120, 256, 0, stream>>>(X, Xb, Wq, Wk, Wv, Wo, Wqt, Wkt, Wvt, Wot);

    const float qs = 0.125f * 1.4426950408889634f;  // (1/sqrt(64)) * log2(e)
    gemm_qkv<<<dim3(12, 64), 256, 0, stream>>>(Xb, Wqt, bq, bk, bv, Qb, Kb, Vtb, qs);
    flash<<<dim3(32, 16), 256, 0, stream>>>(Qb, Kb, Vtb, Atb);
    gemm_out<<<dim3(8, 64), 256, 0, stream>>>(Atb, Wot, bo, out);
}